// Round 13
// baseline (458.472 us; speedup 1.0000x reference)
//
#include <hip/hip_runtime.h>
#include <hip/hip_bf16.h>
#include <stdint.h>

// Problem constants
#define B_ 32
#define N_ 4096
#define M_ 256
#define L_ 128
#define H_ 4
#define BN_ (B_ * N_)          // 131072 flattened rows

typedef __bf16 bf16x8 __attribute__((ext_vector_type(8)));
typedef float  f32x4  __attribute__((ext_vector_type(4)));

__device__ __forceinline__ unsigned short f2bf(float f) {
    unsigned int u = __float_as_uint(f);
    u += 0x7fffu + ((u >> 16) & 1u);
    return (unsigned short)(u >> 16);
}
__device__ __forceinline__ unsigned int pack2(float lo, float hi) {
    return (unsigned int)f2bf(lo) | ((unsigned int)f2bf(hi) << 16);
}

// async global->LDS, 16B/lane; LDS dest wave-uniform base + lane*16 (HW);
// global src per-lane (m173: pre-permute SOURCE to realize a swizzled layout).
__device__ __forceinline__ void gload16(const void* g, void* l) {
    __builtin_amdgcn_global_load_lds(
        (const __attribute__((address_space(1))) unsigned int*)g,
        (__attribute__((address_space(3))) unsigned int*)l, 16, 0, 0);
}

// ---------------------------------------------------------------------------
// prep: V,U (H,M,L) f32 -> vu 8KB images [(h*8 + s)*2 + mat][128 l][32 m]
// bf16, swizzle byte ^= (l&14)<<3, PRESCALED (V*=2, U*=-1) so the GEMM
// epilogue is A=exp(accV)=e^{2v}, E=exp(accU)=e^{-u}.
// ---------------------------------------------------------------------------
__global__ void prep_vu_img(const float* __restrict__ V, const float* __restrict__ U,
                            unsigned short* __restrict__ vu) {
    __shared__ float slab[64][129];     // [m][l], padded
    const int b   = blockIdx.x;         // 32 = h(4) * ks64(4) * mat(2)
    const int mat = b & 1, ks = (b >> 1) & 3, h = b >> 3;
    const float* src = (mat ? U : V) + ((size_t)h * M_ + ks * 64) * L_;
    const float scale = mat ? -1.0f : 2.0f;
    const int tid = threadIdx.x;
#pragma unroll
    for (int rep = 0; rep < 32; ++rep) {
        int idx = rep * 256 + tid;      // 8192 = 64m x 128l
        slab[idx >> 7][idx & 127] = scale * src[(size_t)(idx >> 7) * L_ + (idx & 127)];
    }
    __syncthreads();
#pragma unroll
    for (int rep = 0; rep < 4; ++rep) {
        int cidx = rep * 256 + tid;     // 1024 chunks of 16B (two 8KB images)
        int l  = cidx >> 3;             // 0..127
        int kk = (cidx & 7) * 8;        // 0..56
        uint4 o;
        o.x = pack2(slab[kk + 0][l], slab[kk + 1][l]);
        o.y = pack2(slab[kk + 2][l], slab[kk + 3][l]);
        o.z = pack2(slab[kk + 4][l], slab[kk + 5][l]);
        o.w = pack2(slab[kk + 6][l], slab[kk + 7][l]);
        int tl = kk >> 5, kl = kk & 31;
        char* dst = (char*)vu + (((size_t)(h * 8 + ks * 2 + tl)) * 2 + mat) * 8192;
        int byte = (l * 64 + kl * 2) ^ ((l & 14) << 3);
        *(uint4*)(dst + byte) = o;
    }
}

// ---------------------------------------------------------------------------
// gemm_fast12: 8-wave (512-thread) block, 128 rows x 128 l x {V,U}, one
// (tile,h). Wave wv = (wr=wv>>1, lhh=wv&1): 32 rows x 64 l. acc = 64 VGPR.
// xs single-buffered f32 (16KB, amortized over 8 waves); B dbuf (32KB).
// LDS 49KB -> 3 blocks/CU = 24 waves/CU (75% theoretical occupancy).
// Two barriers per step (r12 schedule):
//   [vmcnt(0)][bar1] [A-frags f32->regs->bf16][lgkmcnt(0)][bar2]
//   [stage x(t+1) same buffer + B(t+1) dbuf] [16 MFMA, B from stable dbuf]
// Writes FULL logits (no partial-logit pass).
// ---------------------------------------------------------------------------
__global__ __launch_bounds__(512, 6)
void gemm_fast12(const float* __restrict__ x,
                 const unsigned short* __restrict__ vu,
                 const float* __restrict__ w,
                 float* __restrict__ logits) {
    __shared__ __align__(16) float          xs[4096];      // 16KB single buffer
    __shared__ __align__(16) unsigned short vs[2][4096];   // 2 x 8KB
    __shared__ __align__(16) unsigned short us[2][4096];   // 2 x 8KB
    __shared__ float part[2][128];                         // 1KB

    const int orig    = blockIdx.x;                 // 4096, %8==0 -> bijective
    const int logical = (orig & 7) * 512 + (orig >> 3);
    const int tile    = logical >> 2;
    const int h       = logical & 3;

    const int tid  = threadIdx.x;
    const int lane = tid & 63;
    const int wv   = tid >> 6;      // 0..7
    const int g    = lane >> 4;     // k-group 0..3
    const int c    = lane & 15;     // row (A) / col (B) within fragment
    const int wr   = wv >> 1;       // row group 0..3 (32 rows each)
    const int lhh  = wv & 1;        // l half

    f32x4 accV[2][4], accU[2][4];   // 64 VGPR
#pragma unroll
    for (int rf = 0; rf < 2; ++rf)
#pragma unroll
        for (int cf = 0; cf < 4; ++cf) {
            accV[rf][cf] = (f32x4){0.f, 0.f, 0.f, 0.f};
            accU[rf][cf] = (f32x4){0.f, 0.f, 0.f, 0.f};
        }

    // ---- B global sources: 8KB images; step stride 16384B (v then u) ----
    const char* gvs = (const char*)vu + (size_t)h * 131072 + wv * 1024 + lane * 16;
    const char* gus = gvs + 8192;

    // ---- x staging source (inverse-swizzled per-lane addresses) ----
    // dest s = wv*2048 + j*1024 + lane*16 -> row = wv*16 + j*8 + (lane>>3);
    // lds[row][o] holds x[row][o ^ ((row&14)<<3)]. src inner byte:
    //   (lane&7)*16 ^ (((lane>>3)&6)<<3) ^ (j<<6).
    const int offb = ((lane & 7) << 4) ^ (((lane >> 3) & 6) << 3);
    const char* pA = (const char*)x
        + ((size_t)tile * 128 + wv * 16 + (lane >> 3)) * 1024 + offb;          // j=0
    const char* pB = (const char*)x
        + ((size_t)tile * 128 + wv * 16 + 8 + (lane >> 3)) * 1024 + (offb ^ 64); // j=1

    // ---- LDS read offsets ----
    int aoff[2], boff[4];
#pragma unroll
    for (int rf = 0; rf < 2; ++rf) {
        int r = wr * 32 + rf * 16 + c;
        aoff[rf] = (r * 128 + g * 32) ^ ((r & 14) << 3);
    }
#pragma unroll
    for (int cf = 0; cf < 4; ++cf) {
        int l = lhh * 64 + cf * 16 + c;
        boff[cf] = (l * 64 + g * 16) ^ ((l & 14) << 3);
    }

#define SCHED __builtin_amdgcn_sched_barrier(0)

#define STAGEX(t) do {                                                   \
        char* _d = (char*)xs + wv * 2048;                                \
        gload16(pA + (t) * 128, _d);                                     \
        gload16(pB + (t) * 128, _d + 1024);                              \
    } while (0)

#define STAGEB(t, bufi) do {                                             \
        gload16(gvs + (t) * 16384, (char*)vs[bufi] + wv * 1024);         \
        gload16(gus + (t) * 16384, (char*)us[bufi] + wv * 1024);         \
    } while (0)

    // prologue: stage step 0 (4 loads per wave)
    STAGEX(0);
    STAGEB(0, 0);
    SCHED;

#pragma unroll
    for (int t = 0; t < 8; ++t) {
        asm volatile("s_waitcnt vmcnt(0)" ::: "memory");  // x(t)+B(t) landed
        __builtin_amdgcn_s_barrier();                     // barrier 1
        SCHED;

        // ---- A-frags: f32 LDS -> regs -> bf16 (before xs is recycled) ----
        bf16x8 a0, a1;
        {
            f32x4 p = *(const f32x4*)((const char*)xs + aoff[0]);
            f32x4 q = *(const f32x4*)((const char*)xs + (aoff[0] ^ 16));
            a0[0] = (__bf16)p.x; a0[1] = (__bf16)p.y;
            a0[2] = (__bf16)p.z; a0[3] = (__bf16)p.w;
            a0[4] = (__bf16)q.x; a0[5] = (__bf16)q.y;
            a0[6] = (__bf16)q.z; a0[7] = (__bf16)q.w;
            p = *(const f32x4*)((const char*)xs + aoff[1]);
            q = *(const f32x4*)((const char*)xs + (aoff[1] ^ 16));
            a1[0] = (__bf16)p.x; a1[1] = (__bf16)p.y;
            a1[2] = (__bf16)p.z; a1[3] = (__bf16)p.w;
            a1[4] = (__bf16)q.x; a1[5] = (__bf16)q.y;
            a1[6] = (__bf16)q.z; a1[7] = (__bf16)q.w;
        }

        if (t < 7) {
            asm volatile("s_waitcnt lgkmcnt(0)" ::: "memory");
            SCHED;
            __builtin_amdgcn_s_barrier();                 // barrier 2: xs free
            SCHED;
            STAGEX(t + 1);                                // same buffer, safe
            STAGEB(t + 1, (t + 1) & 1);
            SCHED;
        }

        const int buf = t & 1;          // compile-time after unroll
        const char* vbuf = (const char*)vs[buf];
        const char* ubuf = (const char*)us[buf];

        __builtin_amdgcn_s_setprio(1);
#pragma unroll
        for (int cf = 0; cf < 4; ++cf) {
            bf16x8 bv = *(const bf16x8*)(vbuf + boff[cf]);
            bf16x8 bu = *(const bf16x8*)(ubuf + boff[cf]);
            accV[0][cf] = __builtin_amdgcn_mfma_f32_16x16x32_bf16(a0, bv, accV[0][cf], 0, 0, 0);
            accV[1][cf] = __builtin_amdgcn_mfma_f32_16x16x32_bf16(a1, bv, accV[1][cf], 0, 0, 0);
            accU[0][cf] = __builtin_amdgcn_mfma_f32_16x16x32_bf16(a0, bu, accU[0][cf], 0, 0, 0);
            accU[1][cf] = __builtin_amdgcn_mfma_f32_16x16x32_bf16(a1, bu, accU[1][cf], 0, 0, 0);
        }
        __builtin_amdgcn_s_setprio(0);
    }
#undef STAGEB
#undef STAGEX
#undef SCHED

    // ---- epilogue: V prescaled 2, U prescaled -1 -> A=e^{2v}, E=e^{-u};
    //      gated=(A-1)/((A+1)(1+E)); dot w over wave's 64 l; 16-lane shuffle
    //      reduce; join the two l-halves via part[]; write FULL logits.
    const float* wrow = w + h * L_ + lhh * 64;
#pragma unroll
    for (int rf = 0; rf < 2; ++rf) {
        float plog[4] = {0.f, 0.f, 0.f, 0.f};
#pragma unroll
        for (int cf = 0; cf < 4; ++cf) {
            float wvv = wrow[cf * 16 + c];
#pragma unroll
            for (int i = 0; i < 4; ++i) {
                float A = __expf(accV[rf][cf][i]);
                float E = __expf(accU[rf][cf][i]);
                float gg = __fdividef(A - 1.f, (A + 1.f) * (1.f + E));
                plog[i] += gg * wvv;
            }
        }
#pragma unroll
        for (int i = 0; i < 4; ++i) {
            float v = plog[i];
            v += __shfl_xor(v, 1);
            v += __shfl_xor(v, 2);
            v += __shfl_xor(v, 4);
            v += __shfl_xor(v, 8);      // sum over the 16 col-lanes
            if (c == 0)
                part[lhh][wr * 32 + rf * 16 + g * 4 + i] = v;
        }
    }
    __syncthreads();
    if (tid < 128) {
        float v = part[0][tid] + part[1][tid];
        int rowflat = tile * 128 + tid;
        int b = rowflat >> 12;           // / N_
        int n = rowflat & (N_ - 1);
        logits[((size_t)b * H_ + h) * N_ + n] = v;
    }
}

// ---------------------------------------------------------------------------
// SLOW PATH (round-1 fallback)
// ---------------------------------------------------------------------------
__global__ void prep_vu_slow(const float* __restrict__ V, const float* __restrict__ U,
                             unsigned short* __restrict__ Vt, unsigned short* __restrict__ Ut) {
    int idx = blockIdx.x * 256 + threadIdx.x;
    int m = idx & (M_ - 1);
    int l = (idx >> 8) & (L_ - 1);
    int h = idx >> 15;
    Vt[idx] = f2bf(V[((size_t)h * M_ + m) * L_ + l]);
    Ut[idx] = f2bf(U[((size_t)h * M_ + m) * L_ + l]);
}

#define BM 128
#define BK 64

__global__ __launch_bounds__(256, 2)
void gemm_logits(const float* __restrict__ x,
                 const unsigned short* __restrict__ Vt,
                 const unsigned short* __restrict__ Ut,
                 const float* __restrict__ w,
                 float* __restrict__ logits) {
    __shared__ __align__(16) unsigned short xs[BM * BK];
    __shared__ __align__(16) unsigned short vs[L_ * BK];
    __shared__ __align__(16) unsigned short us[L_ * BK];
    __shared__ float wl[L_];

    const int h    = blockIdx.x >> 10;
    const int tile = blockIdx.x & 1023;
    const int row0 = tile * BM;
    const int tid  = threadIdx.x;
    const int lane = tid & 63;
    const int wave = tid >> 6;

    if (tid < L_) wl[tid] = w[h * L_ + tid];

    f32x4 accV[2][8], accU[2][8];
#pragma unroll
    for (int rf = 0; rf < 2; ++rf)
#pragma unroll
        for (int cf = 0; cf < 8; ++cf) {
            accV[rf][cf] = (f32x4){0.f, 0.f, 0.f, 0.f};
            accU[rf][cf] = (f32x4){0.f, 0.f, 0.f, 0.f};
        }

    const unsigned short* Vh = Vt + (size_t)h * L_ * M_;
    const unsigned short* Uh = Ut + (size_t)h * L_ * M_;
    const int g = lane >> 4;
    const int c = lane & 15;

    for (int ks = 0; ks < 4; ++ks) {
        const int k0 = ks * BK;
        __syncthreads();
#pragma unroll
        for (int p = 0; p < 4; ++p) {
            int row = p * 32 + (tid >> 3);
            int kk  = (tid & 7) * 8;
            const float* gx = x + (size_t)(row0 + row) * M_ + k0 + kk;
            float4 a = *(const float4*)gx;
            float4 b = *(const float4*)(gx + 4);
            uint4 o;
            o.x = pack2(a.x, a.y); o.y = pack2(a.z, a.w);
            o.z = pack2(b.x, b.y); o.w = pack2(b.z, b.w);
            int byte = (row * BK + kk) * 2;
            byte ^= (row & 7) << 4;
            *(uint4*)((char*)xs + byte) = o;
        }
#pragma unroll
        for (int p = 0; p < 4; ++p) {
            int l  = p * 32 + (tid >> 3);
            int kk = (tid & 7) * 8;
            uint4 v = *(const uint4*)(Vh + (size_t)l * M_ + k0 + kk);
            uint4 u = *(const uint4*)(Uh + (size_t)l * M_ + k0 + kk);
            int byte = (l * BK + kk) * 2;
            byte ^= (l & 7) << 4;
            *(uint4*)((char*)vs + byte) = v;
            *(uint4*)((char*)us + byte) = u;
        }
        __syncthreads();
#pragma unroll
        for (int ksub = 0; ksub < 2; ++ksub) {
            bf16x8 afr[2];
#pragma unroll
            for (int rf = 0; rf < 2; ++rf) {
                int row = wave * 32 + rf * 16 + c;
                int byte = (row * BK + ksub * 32 + g * 8) * 2;
                byte ^= (row & 7) << 4;
                afr[rf] = *(const bf16x8*)((const char*)xs + byte);
            }
#pragma unroll
            for (int cf = 0; cf < 8; ++cf) {
                int l = cf * 16 + c;
                int byte = (l * BK + ksub * 32 + g * 8) * 2;
                byte ^= (l & 7) << 4;
                bf16x8 bv = *(const bf16x8*)((const char*)vs + byte);
                bf16x8 bu = *(const bf16x8*)((const char*)us + byte);
#pragma unroll
                for (int rf = 0; rf < 2; ++rf) {
                    accV[rf][cf] = __builtin_amdgcn_mfma_f32_16x16x32_bf16(afr[rf], bv, accV[rf][cf], 0, 0, 0);
                    accU[rf][cf] = __builtin_amdgcn_mfma_f32_16x16x32_bf16(afr[rf], bu, accU[rf][cf], 0, 0, 0);
                }
            }
        }
    }
#pragma unroll
    for (int rf = 0; rf < 2; ++rf) {
        float plog[4] = {0.f, 0.f, 0.f, 0.f};
#pragma unroll
        for (int cf = 0; cf < 8; ++cf) {
            float wvv = wl[cf * 16 + c];
#pragma unroll
            for (int i = 0; i < 4; ++i) {
                float vv = accV[rf][cf][i];
                float uu = accU[rf][cf][i];
                vv = fminf(fmaxf(vv, -20.f), 20.f);
                float e2v = __expf(2.f * vv);
                float t = __fdividef(e2v - 1.f, e2v + 1.f);
                float s = __fdividef(1.f, 1.f + __expf(-uu));
                plog[i] += t * s * wvv;
            }
        }
#pragma unroll
        for (int i = 0; i < 4; ++i) {
            float v = plog[i];
            v += __shfl_xor(v, 1);
            v += __shfl_xor(v, 2);
            v += __shfl_xor(v, 4);
            v += __shfl_xor(v, 8);
            if (c == 0) {
                int rowflat = row0 + wave * 32 + rf * 16 + g * 4 + i;
                int b = rowflat >> 12;
                int n = rowflat & (N_ - 1);
                logits[((size_t)b * H_ + h) * N_ + n] = v;
            }
        }
    }
}

// ---------------------------------------------------------------------------
// softmax^2 (first normalization cancels): a = e^2/sum(e^2), e = m*exp(m*l).
// ---------------------------------------------------------------------------
__global__ __launch_bounds__(256)
void softmax_att(const float* __restrict__ logits, const float* __restrict__ masks,
                 float* __restrict__ att) {
    const int bh = blockIdx.x;
    const int b = bh >> 2, h = bh & 3;
    __shared__ float e2s[N_];
    __shared__ float red[4];
    const int tid = threadIdx.x;

    float sum = 0.f;
#pragma unroll
    for (int i = 0; i < N_ / 256; ++i) {
        int n = i * 256 + tid;
        float lg = logits[((size_t)b * H_ + h) * N_ + n];
        float mv = masks[(size_t)b * N_ + n];
        float e = mv * __expf(mv * lg);
        float e2 = e * e;
        e2s[n] = e2;
        sum += e2;
    }
#pragma unroll
    for (int off = 32; off >= 1; off >>= 1) sum += __shfl_xor(sum, off);
    if ((tid & 63) == 0) red[tid >> 6] = sum;
    __syncthreads();
    float S = red[0] + red[1] + red[2] + red[3];
    float inv = 1.f / S;
#pragma unroll
    for (int i = 0; i < N_ / 256; ++i) {
        int n = i * 256 + tid;
        att[((size_t)h * B_ + b) * N_ + n] = e2s[n] * inv;
    }
}

// ---------------------------------------------------------------------------
// emb: 2-stage deterministic reduction.
// ---------------------------------------------------------------------------
#define NCH 32
#define CHUNK (N_ / NCH)   // 128

__global__ __launch_bounds__(256)
void emb_partial(const float* __restrict__ x, const float* __restrict__ att,
                 float* __restrict__ part) {
    const int bc = blockIdx.x;
    const int b = bc >> 5, ch = bc & 31;
    __shared__ float as[H_][CHUNK];
    const int tid = threadIdx.x;

    for (int i = tid; i < H_ * CHUNK; i += 256) {
        int hh = i >> 7;
        int j  = i & (CHUNK - 1);
        as[hh][j] = att[((size_t)hh * B_ + b) * N_ + ch * CHUNK + j];
    }
    __syncthreads();

    float a0 = 0.f, a1 = 0.f, a2 = 0.f, a3 = 0.f;
    const float* xp = x + ((size_t)b * N_ + ch * CHUNK) * M_ + tid;
#pragma unroll 4
    for (int j = 0; j < CHUNK; ++j) {
        float xv = xp[(size_t)j * M_];
        a0 += as[0][j] * xv;
        a1 += as[1][j] * xv;
        a2 += as[2][j] * xv;
        a3 += as[3][j] * xv;
    }
    float* pp = part + (size_t)bc * H_ * M_ + tid;
    pp[0 * M_] = a0; pp[1 * M_] = a1; pp[2 * M_] = a2; pp[3 * M_] = a3;
}

__global__ __launch_bounds__(256)
void emb_reduce(const float* __restrict__ part, float* __restrict__ emb) {
    int idx = blockIdx.x * 256 + threadIdx.x;
    int b = idx >> 10;
    int r = idx & 1023;
    float s = 0.f;
#pragma unroll
    for (int ci = 0; ci < NCH; ++ci)
        s += part[((size_t)(b * NCH + ci)) * (H_ * M_) + r];
    emb[idx] = s;
}

// ---------------------------------------------------------------------------
extern "C" void kernel_launch(void* const* d_in, const int* in_sizes, int n_in,
                              void* d_out, int out_size, void* d_ws, size_t ws_size,
                              hipStream_t stream) {
    const float* x     = (const float*)d_in[0];
    const float* masks = (const float*)d_in[1];
    const float* V     = (const float*)d_in[2];
    const float* U     = (const float*)d_in[3];
    const float* w     = (const float*)d_in[4];

    float* att = (float*)d_out;                       // (H,B,N,1)
    float* emb = att + (size_t)H_ * B_ * N_;          // (B,H*M)

    char* ws = (char*)d_ws;
    const size_t VU_BYTES  = (size_t)64 * 8192;               // 524,288
    const size_t LG_BYTES  = (size_t)B_ * H_ * N_ * 4;        // 2,097,152
    const size_t PT_BYTES  = (size_t)B_ * NCH * H_ * M_ * 4;  // 4,194,304
    const size_t NEED_FAST = VU_BYTES + LG_BYTES + PT_BYTES;

    float* logits;
    float* partp;

    if (ws_size >= NEED_FAST) {
        unsigned short* vuimg = (unsigned short*)ws;
        logits = (float*)(ws + VU_BYTES);
        partp  = (float*)(ws + VU_BYTES + LG_BYTES);

        prep_vu_img<<<32,   256, 0, stream>>>(V, U, vuimg);
        gemm_fast12<<<4096, 512, 0, stream>>>(x, vuimg, w, logits);
    } else {
        unsigned short* Vt = (unsigned short*)ws;
        unsigned short* Ut = (unsigned short*)(ws + 262144);
        logits = (float*)(ws + 524288);
        partp  = (float*)(ws + 524288 + LG_BYTES);

        prep_vu_slow<<<512, 256, 0, stream>>>(V, U, Vt, Ut);
        gemm_logits <<<4096, 256, 0, stream>>>(x, Vt, Ut, w, logits);
    }

    softmax_att<<<B_ * H_,              256, 0, stream>>>(logits, masks, att);
    emb_partial<<<B_ * NCH,             256, 0, stream>>>(x, att, partp);
    emb_reduce <<<(B_ * H_ * M_) / 256, 256, 0, stream>>>(partp, emb);
}

// Round 14
// 152.522 us; speedup vs baseline: 3.0059x; 3.0059x over previous
//
#include <hip/hip_runtime.h>
#include <hip/hip_bf16.h>
#include <stdint.h>

// Problem constants
#define B_ 32
#define N_ 4096
#define M_ 256
#define L_ 128
#define H_ 4
#define BN_ (B_ * N_)          // 131072 flattened rows

typedef __bf16 bf16x8 __attribute__((ext_vector_type(8)));
typedef float  f32x4  __attribute__((ext_vector_type(4)));

__device__ __forceinline__ unsigned short f2bf(float f) {
    unsigned int u = __float_as_uint(f);
    u += 0x7fffu + ((u >> 16) & 1u);
    return (unsigned short)(u >> 16);
}
__device__ __forceinline__ unsigned int pack2(float lo, float hi) {
    return (unsigned int)f2bf(lo) | ((unsigned int)f2bf(hi) << 16);
}

// async global->LDS, 16B/lane; LDS dest wave-uniform base + lane*16 (HW);
// global src per-lane (m173: pre-permute SOURCE to realize a swizzled layout).
__device__ __forceinline__ void gload16(const void* g, void* l) {
    __builtin_amdgcn_global_load_lds(
        (const __attribute__((address_space(1))) unsigned int*)g,
        (__attribute__((address_space(3))) unsigned int*)l, 16, 0, 0);
}

// ---------------------------------------------------------------------------
// prep: V,U (H,M,L) f32 -> vu 8KB images [(h*8 + s)*2 + mat][128 l][32 m]
// bf16, swizzle byte ^= (l&14)<<3, PRESCALED (V*=2, U*=-1) so the GEMM
// epilogue is A=exp(accV)=e^{2v}, E=exp(accU)=e^{-u}.
// ---------------------------------------------------------------------------
__global__ void prep_vu_img(const float* __restrict__ V, const float* __restrict__ U,
                            unsigned short* __restrict__ vu) {
    __shared__ float slab[64][129];     // [m][l], padded
    const int b   = blockIdx.x;         // 32 = h(4) * ks64(4) * mat(2)
    const int mat = b & 1, ks = (b >> 1) & 3, h = b >> 3;
    const float* src = (mat ? U : V) + ((size_t)h * M_ + ks * 64) * L_;
    const float scale = mat ? -1.0f : 2.0f;
    const int tid = threadIdx.x;
#pragma unroll
    for (int rep = 0; rep < 32; ++rep) {
        int idx = rep * 256 + tid;      // 8192 = 64m x 128l
        slab[idx >> 7][idx & 127] = scale * src[(size_t)(idx >> 7) * L_ + (idx & 127)];
    }
    __syncthreads();
#pragma unroll
    for (int rep = 0; rep < 4; ++rep) {
        int cidx = rep * 256 + tid;     // 1024 chunks of 16B (two 8KB images)
        int l  = cidx >> 3;             // 0..127
        int kk = (cidx & 7) * 8;        // 0..56
        uint4 o;
        o.x = pack2(slab[kk + 0][l], slab[kk + 1][l]);
        o.y = pack2(slab[kk + 2][l], slab[kk + 3][l]);
        o.z = pack2(slab[kk + 4][l], slab[kk + 5][l]);
        o.w = pack2(slab[kk + 6][l], slab[kk + 7][l]);
        int tl = kk >> 5, kl = kk & 31;
        char* dst = (char*)vu + (((size_t)(h * 8 + ks * 2 + tl)) * 2 + mat) * 8192;
        int byte = (l * 64 + kl * 2) ^ ((l & 14) << 3);
        *(uint4*)(dst + byte) = o;
    }
}

// ---------------------------------------------------------------------------
// gemm_fast12b: round-13 structure with the REGISTER CAP FIXED.
// 8-wave (512-thread) block, 128 rows x 128 l x {V,U}, one (tile,h).
// Wave wv = (wr=wv>>1, lhh=wv&1): 32 rows x 64 l. acc = 64 VGPR.
// __launch_bounds__(512, 4): VGPR cap 128 (r13's (512,6) capped at ~85 and
// spilled the accumulators -> 2.15GB scratch traffic; this was the 575us).
// xs single-buffered f32 (16KB, amortized over 8 waves); B dbuf (32KB).
// LDS 49KB -> 3 blocks/CU = 24 waves/CU. Two barriers per step:
//   [vmcnt(0)][bar1] [A-frags f32->regs->bf16][lgkmcnt(0)][bar2]
//   [stage x(t+1) same buffer + B(t+1) dbuf] [16 MFMA from stable dbuf]
// Writes FULL logits.
// ---------------------------------------------------------------------------
__global__ __launch_bounds__(512, 4)
void gemm_fast12b(const float* __restrict__ x,
                  const unsigned short* __restrict__ vu,
                  const float* __restrict__ w,
                  float* __restrict__ logits) {
    __shared__ __align__(16) float          xs[4096];      // 16KB single buffer
    __shared__ __align__(16) unsigned short vs[2][4096];   // 2 x 8KB
    __shared__ __align__(16) unsigned short us[2][4096];   // 2 x 8KB
    __shared__ float part[2][128];                         // 1KB

    const int orig    = blockIdx.x;                 // 4096, %8==0 -> bijective
    const int logical = (orig & 7) * 512 + (orig >> 3);
    const int tile    = logical >> 2;
    const int h       = logical & 3;

    const int tid  = threadIdx.x;
    const int lane = tid & 63;
    const int wv   = tid >> 6;      // 0..7
    const int g    = lane >> 4;     // k-group 0..3
    const int c    = lane & 15;     // row (A) / col (B) within fragment
    const int wr   = wv >> 1;       // row group 0..3 (32 rows each)
    const int lhh  = wv & 1;        // l half

    f32x4 accV[2][4], accU[2][4];   // 64 VGPR
#pragma unroll
    for (int rf = 0; rf < 2; ++rf)
#pragma unroll
        for (int cf = 0; cf < 4; ++cf) {
            accV[rf][cf] = (f32x4){0.f, 0.f, 0.f, 0.f};
            accU[rf][cf] = (f32x4){0.f, 0.f, 0.f, 0.f};
        }

    // ---- B global sources: 8KB images; step stride 16384B (v then u) ----
    const char* gvs = (const char*)vu + (size_t)h * 131072 + wv * 1024 + lane * 16;
    const char* gus = gvs + 8192;

    // ---- x staging source (inverse-swizzled per-lane addresses) ----
    // dest s = wv*2048 + j*1024 + lane*16 -> row = wv*16 + j*8 + (lane>>3);
    // lds[row][o] holds x[row][o ^ ((row&14)<<3)]. src inner byte:
    //   (lane&7)*16 ^ (((lane>>3)&6)<<3) ^ (j<<6).
    const int offb = ((lane & 7) << 4) ^ (((lane >> 3) & 6) << 3);
    const char* pA = (const char*)x
        + ((size_t)tile * 128 + wv * 16 + (lane >> 3)) * 1024 + offb;          // j=0
    const char* pB = (const char*)x
        + ((size_t)tile * 128 + wv * 16 + 8 + (lane >> 3)) * 1024 + (offb ^ 64); // j=1

    // ---- LDS read offsets ----
    int aoff[2], boff[4];
#pragma unroll
    for (int rf = 0; rf < 2; ++rf) {
        int r = wr * 32 + rf * 16 + c;
        aoff[rf] = (r * 128 + g * 32) ^ ((r & 14) << 3);
    }
#pragma unroll
    for (int cf = 0; cf < 4; ++cf) {
        int l = lhh * 64 + cf * 16 + c;
        boff[cf] = (l * 64 + g * 16) ^ ((l & 14) << 3);
    }

#define SCHED __builtin_amdgcn_sched_barrier(0)

#define STAGEX(t) do {                                                   \
        char* _d = (char*)xs + wv * 2048;                                \
        gload16(pA + (t) * 128, _d);                                     \
        gload16(pB + (t) * 128, _d + 1024);                              \
    } while (0)

#define STAGEB(t, bufi) do {                                             \
        gload16(gvs + (t) * 16384, (char*)vs[bufi] + wv * 1024);         \
        gload16(gus + (t) * 16384, (char*)us[bufi] + wv * 1024);         \
    } while (0)

    // prologue: stage step 0 (4 loads per wave)
    STAGEX(0);
    STAGEB(0, 0);
    SCHED;

#pragma unroll
    for (int t = 0; t < 8; ++t) {
        asm volatile("s_waitcnt vmcnt(0)" ::: "memory");  // x(t)+B(t) landed
        __builtin_amdgcn_s_barrier();                     // barrier 1
        SCHED;

        // ---- A-frags: f32 LDS -> regs -> bf16 (before xs is recycled) ----
        bf16x8 a0, a1;
        {
            f32x4 p = *(const f32x4*)((const char*)xs + aoff[0]);
            f32x4 q = *(const f32x4*)((const char*)xs + (aoff[0] ^ 16));
            a0[0] = (__bf16)p.x; a0[1] = (__bf16)p.y;
            a0[2] = (__bf16)p.z; a0[3] = (__bf16)p.w;
            a0[4] = (__bf16)q.x; a0[5] = (__bf16)q.y;
            a0[6] = (__bf16)q.z; a0[7] = (__bf16)q.w;
            p = *(const f32x4*)((const char*)xs + aoff[1]);
            q = *(const f32x4*)((const char*)xs + (aoff[1] ^ 16));
            a1[0] = (__bf16)p.x; a1[1] = (__bf16)p.y;
            a1[2] = (__bf16)p.z; a1[3] = (__bf16)p.w;
            a1[4] = (__bf16)q.x; a1[5] = (__bf16)q.y;
            a1[6] = (__bf16)q.z; a1[7] = (__bf16)q.w;
        }

        if (t < 7) {
            asm volatile("s_waitcnt lgkmcnt(0)" ::: "memory");
            SCHED;
            __builtin_amdgcn_s_barrier();                 // barrier 2: xs free
            SCHED;
            STAGEX(t + 1);                                // same buffer, safe
            STAGEB(t + 1, (t + 1) & 1);
            SCHED;
        }

        const int buf = t & 1;          // compile-time after unroll
        const char* vbuf = (const char*)vs[buf];
        const char* ubuf = (const char*)us[buf];

        __builtin_amdgcn_s_setprio(1);
#pragma unroll
        for (int cf = 0; cf < 4; ++cf) {
            bf16x8 bv = *(const bf16x8*)(vbuf + boff[cf]);
            bf16x8 bu = *(const bf16x8*)(ubuf + boff[cf]);
            accV[0][cf] = __builtin_amdgcn_mfma_f32_16x16x32_bf16(a0, bv, accV[0][cf], 0, 0, 0);
            accV[1][cf] = __builtin_amdgcn_mfma_f32_16x16x32_bf16(a1, bv, accV[1][cf], 0, 0, 0);
            accU[0][cf] = __builtin_amdgcn_mfma_f32_16x16x32_bf16(a0, bu, accU[0][cf], 0, 0, 0);
            accU[1][cf] = __builtin_amdgcn_mfma_f32_16x16x32_bf16(a1, bu, accU[1][cf], 0, 0, 0);
        }
        __builtin_amdgcn_s_setprio(0);
    }
#undef STAGEB
#undef STAGEX
#undef SCHED

    // ---- epilogue: V prescaled 2, U prescaled -1 -> A=e^{2v}, E=e^{-u};
    //      gated=(A-1)/((A+1)(1+E)); dot w over wave's 64 l; 16-lane shuffle
    //      reduce; join the two l-halves via part[]; write FULL logits.
    const float* wrow = w + h * L_ + lhh * 64;
#pragma unroll
    for (int rf = 0; rf < 2; ++rf) {
        float plog[4] = {0.f, 0.f, 0.f, 0.f};
#pragma unroll
        for (int cf = 0; cf < 4; ++cf) {
            float wvv = wrow[cf * 16 + c];
#pragma unroll
            for (int i = 0; i < 4; ++i) {
                float A = __expf(accV[rf][cf][i]);
                float E = __expf(accU[rf][cf][i]);
                float gg = __fdividef(A - 1.f, (A + 1.f) * (1.f + E));
                plog[i] += gg * wvv;
            }
        }
#pragma unroll
        for (int i = 0; i < 4; ++i) {
            float v = plog[i];
            v += __shfl_xor(v, 1);
            v += __shfl_xor(v, 2);
            v += __shfl_xor(v, 4);
            v += __shfl_xor(v, 8);      // sum over the 16 col-lanes
            if (c == 0)
                part[lhh][wr * 32 + rf * 16 + g * 4 + i] = v;
        }
    }
    __syncthreads();
    if (tid < 128) {
        float v = part[0][tid] + part[1][tid];
        int rowflat = tile * 128 + tid;
        int b = rowflat >> 12;           // / N_
        int n = rowflat & (N_ - 1);
        logits[((size_t)b * H_ + h) * N_ + n] = v;
    }
}

// ---------------------------------------------------------------------------
// SLOW PATH (round-1 fallback)
// ---------------------------------------------------------------------------
__global__ void prep_vu_slow(const float* __restrict__ V, const float* __restrict__ U,
                             unsigned short* __restrict__ Vt, unsigned short* __restrict__ Ut) {
    int idx = blockIdx.x * 256 + threadIdx.x;
    int m = idx & (M_ - 1);
    int l = (idx >> 8) & (L_ - 1);
    int h = idx >> 15;
    Vt[idx] = f2bf(V[((size_t)h * M_ + m) * L_ + l]);
    Ut[idx] = f2bf(U[((size_t)h * M_ + m) * L_ + l]);
}

#define BM 128
#define BK 64

__global__ __launch_bounds__(256, 2)
void gemm_logits(const float* __restrict__ x,
                 const unsigned short* __restrict__ Vt,
                 const unsigned short* __restrict__ Ut,
                 const float* __restrict__ w,
                 float* __restrict__ logits) {
    __shared__ __align__(16) unsigned short xs[BM * BK];
    __shared__ __align__(16) unsigned short vs[L_ * BK];
    __shared__ __align__(16) unsigned short us[L_ * BK];
    __shared__ float wl[L_];

    const int h    = blockIdx.x >> 10;
    const int tile = blockIdx.x & 1023;
    const int row0 = tile * BM;
    const int tid  = threadIdx.x;
    const int lane = tid & 63;
    const int wave = tid >> 6;

    if (tid < L_) wl[tid] = w[h * L_ + tid];

    f32x4 accV[2][8], accU[2][8];
#pragma unroll
    for (int rf = 0; rf < 2; ++rf)
#pragma unroll
        for (int cf = 0; cf < 8; ++cf) {
            accV[rf][cf] = (f32x4){0.f, 0.f, 0.f, 0.f};
            accU[rf][cf] = (f32x4){0.f, 0.f, 0.f, 0.f};
        }

    const unsigned short* Vh = Vt + (size_t)h * L_ * M_;
    const unsigned short* Uh = Ut + (size_t)h * L_ * M_;
    const int g = lane >> 4;
    const int c = lane & 15;

    for (int ks = 0; ks < 4; ++ks) {
        const int k0 = ks * BK;
        __syncthreads();
#pragma unroll
        for (int p = 0; p < 4; ++p) {
            int row = p * 32 + (tid >> 3);
            int kk  = (tid & 7) * 8;
            const float* gx = x + (size_t)(row0 + row) * M_ + k0 + kk;
            float4 a = *(const float4*)gx;
            float4 b = *(const float4*)(gx + 4);
            uint4 o;
            o.x = pack2(a.x, a.y); o.y = pack2(a.z, a.w);
            o.z = pack2(b.x, b.y); o.w = pack2(b.z, b.w);
            int byte = (row * BK + kk) * 2;
            byte ^= (row & 7) << 4;
            *(uint4*)((char*)xs + byte) = o;
        }
#pragma unroll
        for (int p = 0; p < 4; ++p) {
            int l  = p * 32 + (tid >> 3);
            int kk = (tid & 7) * 8;
            uint4 v = *(const uint4*)(Vh + (size_t)l * M_ + k0 + kk);
            uint4 u = *(const uint4*)(Uh + (size_t)l * M_ + k0 + kk);
            int byte = (l * BK + kk) * 2;
            byte ^= (l & 7) << 4;
            *(uint4*)((char*)vs + byte) = v;
            *(uint4*)((char*)us + byte) = u;
        }
        __syncthreads();
#pragma unroll
        for (int ksub = 0; ksub < 2; ++ksub) {
            bf16x8 afr[2];
#pragma unroll
            for (int rf = 0; rf < 2; ++rf) {
                int row = wave * 32 + rf * 16 + c;
                int byte = (row * BK + ksub * 32 + g * 8) * 2;
                byte ^= (row & 7) << 4;
                afr[rf] = *(const bf16x8*)((const char*)xs + byte);
            }
#pragma unroll
            for (int cf = 0; cf < 8; ++cf) {
                int l = cf * 16 + c;
                int byte = (l * BK + ksub * 32 + g * 8) * 2;
                byte ^= (l & 7) << 4;
                bf16x8 bv = *(const bf16x8*)((const char*)vs + byte);
                bf16x8 bu = *(const bf16x8*)((const char*)us + byte);
#pragma unroll
                for (int rf = 0; rf < 2; ++rf) {
                    accV[rf][cf] = __builtin_amdgcn_mfma_f32_16x16x32_bf16(afr[rf], bv, accV[rf][cf], 0, 0, 0);
                    accU[rf][cf] = __builtin_amdgcn_mfma_f32_16x16x32_bf16(afr[rf], bu, accU[rf][cf], 0, 0, 0);
                }
            }
        }
    }
#pragma unroll
    for (int rf = 0; rf < 2; ++rf) {
        float plog[4] = {0.f, 0.f, 0.f, 0.f};
#pragma unroll
        for (int cf = 0; cf < 8; ++cf) {
            float wvv = wl[cf * 16 + c];
#pragma unroll
            for (int i = 0; i < 4; ++i) {
                float vv = accV[rf][cf][i];
                float uu = accU[rf][cf][i];
                vv = fminf(fmaxf(vv, -20.f), 20.f);
                float e2v = __expf(2.f * vv);
                float t = __fdividef(e2v - 1.f, e2v + 1.f);
                float s = __fdividef(1.f, 1.f + __expf(-uu));
                plog[i] += t * s * wvv;
            }
        }
#pragma unroll
        for (int i = 0; i < 4; ++i) {
            float v = plog[i];
            v += __shfl_xor(v, 1);
            v += __shfl_xor(v, 2);
            v += __shfl_xor(v, 4);
            v += __shfl_xor(v, 8);
            if (c == 0) {
                int rowflat = row0 + wave * 32 + rf * 16 + g * 4 + i;
                int b = rowflat >> 12;
                int n = rowflat & (N_ - 1);
                logits[((size_t)b * H_ + h) * N_ + n] = v;
            }
        }
    }
}

// ---------------------------------------------------------------------------
// softmax^2 (first normalization cancels): a = e^2/sum(e^2), e = m*exp(m*l).
// ---------------------------------------------------------------------------
__global__ __launch_bounds__(256)
void softmax_att(const float* __restrict__ logits, const float* __restrict__ masks,
                 float* __restrict__ att) {
    const int bh = blockIdx.x;
    const int b = bh >> 2, h = bh & 3;
    __shared__ float e2s[N_];
    __shared__ float red[4];
    const int tid = threadIdx.x;

    float sum = 0.f;
#pragma unroll
    for (int i = 0; i < N_ / 256; ++i) {
        int n = i * 256 + tid;
        float lg = logits[((size_t)b * H_ + h) * N_ + n];
        float mv = masks[(size_t)b * N_ + n];
        float e = mv * __expf(mv * lg);
        float e2 = e * e;
        e2s[n] = e2;
        sum += e2;
    }
#pragma unroll
    for (int off = 32; off >= 1; off >>= 1) sum += __shfl_xor(sum, off);
    if ((tid & 63) == 0) red[tid >> 6] = sum;
    __syncthreads();
    float S = red[0] + red[1] + red[2] + red[3];
    float inv = 1.f / S;
#pragma unroll
    for (int i = 0; i < N_ / 256; ++i) {
        int n = i * 256 + tid;
        att[((size_t)h * B_ + b) * N_ + n] = e2s[n] * inv;
    }
}

// ---------------------------------------------------------------------------
// emb: 2-stage deterministic reduction.
// ---------------------------------------------------------------------------
#define NCH 32
#define CHUNK (N_ / NCH)   // 128

__global__ __launch_bounds__(256)
void emb_partial(const float* __restrict__ x, const float* __restrict__ att,
                 float* __restrict__ part) {
    const int bc = blockIdx.x;
    const int b = bc >> 5, ch = bc & 31;
    __shared__ float as[H_][CHUNK];
    const int tid = threadIdx.x;

    for (int i = tid; i < H_ * CHUNK; i += 256) {
        int hh = i >> 7;
        int j  = i & (CHUNK - 1);
        as[hh][j] = att[((size_t)hh * B_ + b) * N_ + ch * CHUNK + j];
    }
    __syncthreads();

    float a0 = 0.f, a1 = 0.f, a2 = 0.f, a3 = 0.f;
    const float* xp = x + ((size_t)b * N_ + ch * CHUNK) * M_ + tid;
#pragma unroll 4
    for (int j = 0; j < CHUNK; ++j) {
        float xv = xp[(size_t)j * M_];
        a0 += as[0][j] * xv;
        a1 += as[1][j] * xv;
        a2 += as[2][j] * xv;
        a3 += as[3][j] * xv;
    }
    float* pp = part + (size_t)bc * H_ * M_ + tid;
    pp[0 * M_] = a0; pp[1 * M_] = a1; pp[2 * M_] = a2; pp[3 * M_] = a3;
}

__global__ __launch_bounds__(256)
void emb_reduce(const float* __restrict__ part, float* __restrict__ emb) {
    int idx = blockIdx.x * 256 + threadIdx.x;
    int b = idx >> 10;
    int r = idx & 1023;
    float s = 0.f;
#pragma unroll
    for (int ci = 0; ci < NCH; ++ci)
        s += part[((size_t)(b * NCH + ci)) * (H_ * M_) + r];
    emb[idx] = s;
}

// ---------------------------------------------------------------------------
extern "C" void kernel_launch(void* const* d_in, const int* in_sizes, int n_in,
                              void* d_out, int out_size, void* d_ws, size_t ws_size,
                              hipStream_t stream) {
    const float* x     = (const float*)d_in[0];
    const float* masks = (const float*)d_in[1];
    const float* V     = (const float*)d_in[2];
    const float* U     = (const float*)d_in[3];
    const float* w     = (const float*)d_in[4];

    float* att = (float*)d_out;                       // (H,B,N,1)
    float* emb = att + (size_t)H_ * B_ * N_;          // (B,H*M)

    char* ws = (char*)d_ws;
    const size_t VU_BYTES  = (size_t)64 * 8192;               // 524,288
    const size_t LG_BYTES  = (size_t)B_ * H_ * N_ * 4;        // 2,097,152
    const size_t PT_BYTES  = (size_t)B_ * NCH * H_ * M_ * 4;  // 4,194,304
    const size_t NEED_FAST = VU_BYTES + LG_BYTES + PT_BYTES;

    float* logits;
    float* partp;

    if (ws_size >= NEED_FAST) {
        unsigned short* vuimg = (unsigned short*)ws;
        logits = (float*)(ws + VU_BYTES);
        partp  = (float*)(ws + VU_BYTES + LG_BYTES);

        prep_vu_img <<<32,   256, 0, stream>>>(V, U, vuimg);
        gemm_fast12b<<<4096, 512, 0, stream>>>(x, vuimg, w, logits);
    } else {
        unsigned short* Vt = (unsigned short*)ws;
        unsigned short* Ut = (unsigned short*)(ws + 262144);
        logits = (float*)(ws + 524288);
        partp  = (float*)(ws + 524288 + LG_BYTES);

        prep_vu_slow<<<512, 256, 0, stream>>>(V, U, Vt, Ut);
        gemm_logits <<<4096, 256, 0, stream>>>(x, Vt, Ut, w, logits);
    }

    softmax_att<<<B_ * H_,              256, 0, stream>>>(logits, masks, att);
    emb_partial<<<B_ * NCH,             256, 0, stream>>>(x, att, partp);
    emb_reduce <<<(B_ * H_ * M_) / 256, 256, 0, stream>>>(partp, emb);
}

// Round 15
// 151.362 us; speedup vs baseline: 3.0290x; 1.0077x over previous
//
#include <hip/hip_runtime.h>
#include <hip/hip_bf16.h>
#include <stdint.h>

// Problem constants
#define B_ 32
#define N_ 4096
#define M_ 256
#define L_ 128
#define H_ 4
#define BN_ (B_ * N_)          // 131072 flattened rows

typedef __bf16 bf16x8 __attribute__((ext_vector_type(8)));
typedef float  f32x4  __attribute__((ext_vector_type(4)));

__device__ __forceinline__ unsigned short f2bf(float f) {
    unsigned int u = __float_as_uint(f);
    u += 0x7fffu + ((u >> 16) & 1u);
    return (unsigned short)(u >> 16);
}
__device__ __forceinline__ unsigned int pack2(float lo, float hi) {
    return (unsigned int)f2bf(lo) | ((unsigned int)f2bf(hi) << 16);
}

// async global->LDS, 16B/lane; LDS dest wave-uniform base + lane*16 (HW);
// global src per-lane (m173: pre-permute SOURCE to realize a swizzled layout).
__device__ __forceinline__ void gload16(const void* g, void* l) {
    __builtin_amdgcn_global_load_lds(
        (const __attribute__((address_space(1))) unsigned int*)g,
        (__attribute__((address_space(3))) unsigned int*)l, 16, 0, 0);
}

// ---------------------------------------------------------------------------
// prep: V,U (H,M,L) f32 -> vu2 4KB images [(((h*2+lh)*8 + s)*2 + mat)]
// [64 l][32 m] bf16, swizzle byte ^= (ll&14)<<3, PRESCALED (V*=2, U*=-1).
// ---------------------------------------------------------------------------
__global__ void prep_vu_img2(const float* __restrict__ V, const float* __restrict__ U,
                             unsigned short* __restrict__ vu) {
    __shared__ float slab[64][129];     // [m][l], padded
    const int b   = blockIdx.x;         // 32 = h(4) * ks64(4) * mat(2)
    const int mat = b & 1, ks = (b >> 1) & 3, h = b >> 3;
    const float* src = (mat ? U : V) + ((size_t)h * M_ + ks * 64) * L_;
    const float scale = mat ? -1.0f : 2.0f;
    const int tid = threadIdx.x;
#pragma unroll
    for (int rep = 0; rep < 32; ++rep) {
        int idx = rep * 256 + tid;      // 8192 = 64m x 128l
        slab[idx >> 7][idx & 127] = scale * src[(size_t)(idx >> 7) * L_ + (idx & 127)];
    }
    __syncthreads();
#pragma unroll
    for (int rep = 0; rep < 4; ++rep) {
        int cidx = rep * 256 + tid;     // 1024 chunks of 16B
        int l  = cidx >> 3;             // 0..127
        int kk = (cidx & 7) * 8;        // 0..56
        uint4 o;
        o.x = pack2(slab[kk + 0][l], slab[kk + 1][l]);
        o.y = pack2(slab[kk + 2][l], slab[kk + 3][l]);
        o.z = pack2(slab[kk + 4][l], slab[kk + 5][l]);
        o.w = pack2(slab[kk + 6][l], slab[kk + 7][l]);
        int tl = kk >> 5, kl = kk & 31;
        int lh = l >> 6, ll = l & 63;
        char* dst = (char*)vu
            + ((((size_t)(h * 2 + lh) * 8 + (ks * 2 + tl)) * 2) + mat) * 4096;
        int byte = (ll * 64 + kl * 2) ^ ((ll & 14) << 3);
        *(uint4*)(dst + byte) = o;
    }
}

// ---------------------------------------------------------------------------
// gemm_fast13: r12's best kernel with the x-path made WAVE-PRIVATE ->
// barrier2 eliminated (1 barrier per K-step instead of 2).
// Block = 128 rows x 64 l x {V,U} for one (tile,h,lh); 4 waves; wave wv owns
// rows wv*32..+32 (stages AND reads exactly those rows -> recycle hazard is
// ordered by the wave's own lgkmcnt(0), no barrier). B (4KB prescaled bf16
// images) stays cooperatively staged + double-buffered; barrier1 + own-
// vmcnt(0) makes all B(t) visible (B-reads of t-1 completed before their
// consuming MFMAs, which precede barrier1 -> buffer recycle safe).
// Per step: [vmcnt(0)][bar] [4x A ds_read f32 -> cvt bf16][lgkmcnt(0)]
//           [STAGEX(t+1) own region + STAGEB(t+1) other buf]
//           [8x B ds_read + 16 MFMA].
// acc = 64 VGPR; LDS = 16KB xs + 16KB B = 32KB (same as r12, 5 blocks/CU).
// Writes PARTIAL logits (softmax sums the two l-halves).
// ---------------------------------------------------------------------------
__global__ __launch_bounds__(256, 4)
void gemm_fast13(const float* __restrict__ x,
                 const unsigned short* __restrict__ vu,
                 const float* __restrict__ w,
                 float* __restrict__ partL) {
    __shared__ __align__(16) float          xs[4096];      // 16KB, wave-private quarters
    __shared__ __align__(16) unsigned short vs[2][2048];   // 2 x 4KB
    __shared__ __align__(16) unsigned short us[2][2048];   // 2 x 4KB

    const int orig    = blockIdx.x;                 // 8192, %8==0 -> bijective
    const int logical = (orig & 7) * 1024 + (orig >> 3);
    const int tile    = logical >> 3;
    const int h       = (logical >> 1) & 3;
    const int lh      = logical & 1;

    const int tid  = threadIdx.x;
    const int lane = tid & 63;
    const int wv   = tid >> 6;
    const int g    = lane >> 4;     // k-group 0..3
    const int c    = lane & 15;     // row (A) / col (B) within fragment

    f32x4 accV[2][4], accU[2][4];   // 64 VGPR total
#pragma unroll
    for (int rf = 0; rf < 2; ++rf)
#pragma unroll
        for (int cf = 0; cf < 4; ++cf) {
            accV[rf][cf] = (f32x4){0.f, 0.f, 0.f, 0.f};
            accU[rf][cf] = (f32x4){0.f, 0.f, 0.f, 0.f};
        }

    // ---- B global sources: 4KB images, step stride 8192B (v+u) ----
    const char* gvs = (const char*)vu + (size_t)(h * 2 + lh) * 65536
                      + wv * 1024 + lane * 16;
    const char* gus = gvs + 4096;

    // ---- x staging sources (wave-PRIVATE rows wv*32..+32) ----
    // dest s = wv*4096 + j*1024 + lane*16 -> row = wv*32 + j*8 + (lane>>3);
    // lds[row][o] = x[row][o ^ ((row&14)<<3)]; row&14 bits: 1-2 from lane>>3,
    // bit3 from j&1 -> inner = ((lane&7)<<4) ^ (((lane>>3)&6)<<3) ^ ((j&1)<<6).
    const int offb = ((lane & 7) << 4) ^ (((lane >> 3) & 6) << 3);
    const size_t rowbase = (size_t)tile * 128 + wv * 32 + (lane >> 3);
    const char* px0 = (const char*)x + (rowbase +  0) * 1024 + offb;
    const char* px1 = (const char*)x + (rowbase +  8) * 1024 + (offb ^ 64);
    const char* px2 = (const char*)x + (rowbase + 16) * 1024 + offb;
    const char* px3 = (const char*)x + (rowbase + 24) * 1024 + (offb ^ 64);

    // ---- LDS read offsets ----
    // A: r = wv*32 + rf*16 + c -> within own 4KB quarter; r&14 == c&14.
    int aoff[2], boff[4];
#pragma unroll
    for (int rf = 0; rf < 2; ++rf) {
        int r = wv * 32 + rf * 16 + c;
        aoff[rf] = (r * 128 + g * 32) ^ ((r & 14) << 3);
    }
#pragma unroll
    for (int cf = 0; cf < 4; ++cf) {
        int ll = cf * 16 + c;
        boff[cf] = (ll * 64 + g * 16) ^ ((ll & 14) << 3);
    }

#define SCHED __builtin_amdgcn_sched_barrier(0)

#define STAGEX(t) do {                                                   \
        char* _d = (char*)xs + wv * 4096;                                \
        gload16(px0 + (t) * 128, _d);                                    \
        gload16(px1 + (t) * 128, _d + 1024);                             \
        gload16(px2 + (t) * 128, _d + 2048);                             \
        gload16(px3 + (t) * 128, _d + 3072);                             \
    } while (0)

#define STAGEB(t, bufi) do {                                             \
        gload16(gvs + (t) * 8192, (char*)vs[bufi] + wv * 1024);          \
        gload16(gus + (t) * 8192, (char*)us[bufi] + wv * 1024);          \
    } while (0)

    // prologue: stage step 0 (6 loads per wave)
    STAGEX(0);
    STAGEB(0, 0);
    SCHED;

#pragma unroll
    for (int t = 0; t < 8; ++t) {
        asm volatile("s_waitcnt vmcnt(0)" ::: "memory");  // own x(t)+B(t) landed
        __builtin_amdgcn_s_barrier();                     // all waves' B(t) visible
        SCHED;

        // ---- A-frags: f32 LDS (own region) -> regs -> bf16 ----
        bf16x8 a0, a1;
        {
            f32x4 p = *(const f32x4*)((const char*)xs + aoff[0]);
            f32x4 q = *(const f32x4*)((const char*)xs + (aoff[0] ^ 16));
            a0[0] = (__bf16)p.x; a0[1] = (__bf16)p.y;
            a0[2] = (__bf16)p.z; a0[3] = (__bf16)p.w;
            a0[4] = (__bf16)q.x; a0[5] = (__bf16)q.y;
            a0[6] = (__bf16)q.z; a0[7] = (__bf16)q.w;
            p = *(const f32x4*)((const char*)xs + aoff[1]);
            q = *(const f32x4*)((const char*)xs + (aoff[1] ^ 16));
            a1[0] = (__bf16)p.x; a1[1] = (__bf16)p.y;
            a1[2] = (__bf16)p.z; a1[3] = (__bf16)p.w;
            a1[4] = (__bf16)q.x; a1[5] = (__bf16)q.y;
            a1[6] = (__bf16)q.z; a1[7] = (__bf16)q.w;
        }

        if (t < 7) {
            // own A-reads complete -> own xs quarter recyclable (wave-local)
            asm volatile("s_waitcnt lgkmcnt(0)" ::: "memory");
            SCHED;
            STAGEX(t + 1);                 // private region, no barrier needed
            STAGEB(t + 1, (t + 1) & 1);    // other buffer, race-free
            SCHED;
        }

        const int buf = t & 1;          // compile-time after unroll
        const char* vbuf = (const char*)vs[buf];
        const char* ubuf = (const char*)us[buf];

        __builtin_amdgcn_s_setprio(1);
#pragma unroll
        for (int cf = 0; cf < 4; ++cf) {
            bf16x8 bv = *(const bf16x8*)(vbuf + boff[cf]);
            bf16x8 bu = *(const bf16x8*)(ubuf + boff[cf]);
            accV[0][cf] = __builtin_amdgcn_mfma_f32_16x16x32_bf16(a0, bv, accV[0][cf], 0, 0, 0);
            accV[1][cf] = __builtin_amdgcn_mfma_f32_16x16x32_bf16(a1, bv, accV[1][cf], 0, 0, 0);
            accU[0][cf] = __builtin_amdgcn_mfma_f32_16x16x32_bf16(a0, bu, accU[0][cf], 0, 0, 0);
            accU[1][cf] = __builtin_amdgcn_mfma_f32_16x16x32_bf16(a1, bu, accU[1][cf], 0, 0, 0);
        }
        __builtin_amdgcn_s_setprio(0);
    }
#undef STAGEB
#undef STAGEX
#undef SCHED

    // ---- epilogue: V prescaled 2, U prescaled -1 -> A=e^{2v}, E=e^{-u};
    //      gated=(A-1)/((A+1)(1+E)); dot w over this block's 64 l; 16-lane
    //      shuffle reduce; write PARTIAL logits (summed by softmax).
    const float* wrow = w + h * L_ + lh * 64;
    float* pl = partL + (size_t)lh * (B_ * H_ * N_);
#pragma unroll
    for (int rf = 0; rf < 2; ++rf) {
        float plog[4] = {0.f, 0.f, 0.f, 0.f};
#pragma unroll
        for (int cf = 0; cf < 4; ++cf) {
            float wvv = wrow[cf * 16 + c];
#pragma unroll
            for (int i = 0; i < 4; ++i) {
                float A = __expf(accV[rf][cf][i]);
                float E = __expf(accU[rf][cf][i]);
                float gg = __fdividef(A - 1.f, (A + 1.f) * (1.f + E));
                plog[i] += gg * wvv;
            }
        }
#pragma unroll
        for (int i = 0; i < 4; ++i) {
            float v = plog[i];
            v += __shfl_xor(v, 1);
            v += __shfl_xor(v, 2);
            v += __shfl_xor(v, 4);
            v += __shfl_xor(v, 8);      // sum over the 16 col-lanes
            if (c == 0) {
                int rowflat = tile * 128 + wv * 32 + rf * 16 + g * 4 + i;
                int b = rowflat >> 12;
                int n = rowflat & (N_ - 1);
                pl[((size_t)b * H_ + h) * N_ + n] = v;
            }
        }
    }
}

// ---------------------------------------------------------------------------
// SLOW PATH (round-1 fallback)
// ---------------------------------------------------------------------------
__global__ void prep_vu_slow(const float* __restrict__ V, const float* __restrict__ U,
                             unsigned short* __restrict__ Vt, unsigned short* __restrict__ Ut) {
    int idx = blockIdx.x * 256 + threadIdx.x;
    int m = idx & (M_ - 1);
    int l = (idx >> 8) & (L_ - 1);
    int h = idx >> 15;
    Vt[idx] = f2bf(V[((size_t)h * M_ + m) * L_ + l]);
    Ut[idx] = f2bf(U[((size_t)h * M_ + m) * L_ + l]);
}

#define BM 128
#define BK 64

__global__ __launch_bounds__(256, 2)
void gemm_logits(const float* __restrict__ x,
                 const unsigned short* __restrict__ Vt,
                 const unsigned short* __restrict__ Ut,
                 const float* __restrict__ w,
                 float* __restrict__ logits) {
    __shared__ __align__(16) unsigned short xs[BM * BK];
    __shared__ __align__(16) unsigned short vs[L_ * BK];
    __shared__ __align__(16) unsigned short us[L_ * BK];
    __shared__ float wl[L_];

    const int h    = blockIdx.x >> 10;
    const int tile = blockIdx.x & 1023;
    const int row0 = tile * BM;
    const int tid  = threadIdx.x;
    const int lane = tid & 63;
    const int wave = tid >> 6;

    if (tid < L_) wl[tid] = w[h * L_ + tid];

    f32x4 accV[2][8], accU[2][8];
#pragma unroll
    for (int rf = 0; rf < 2; ++rf)
#pragma unroll
        for (int cf = 0; cf < 8; ++cf) {
            accV[rf][cf] = (f32x4){0.f, 0.f, 0.f, 0.f};
            accU[rf][cf] = (f32x4){0.f, 0.f, 0.f, 0.f};
        }

    const unsigned short* Vh = Vt + (size_t)h * L_ * M_;
    const unsigned short* Uh = Ut + (size_t)h * L_ * M_;
    const int g = lane >> 4;
    const int c = lane & 15;

    for (int ks = 0; ks < 4; ++ks) {
        const int k0 = ks * BK;
        __syncthreads();
#pragma unroll
        for (int p = 0; p < 4; ++p) {
            int row = p * 32 + (tid >> 3);
            int kk  = (tid & 7) * 8;
            const float* gx = x + (size_t)(row0 + row) * M_ + k0 + kk;
            float4 a = *(const float4*)gx;
            float4 b = *(const float4*)(gx + 4);
            uint4 o;
            o.x = pack2(a.x, a.y); o.y = pack2(a.z, a.w);
            o.z = pack2(b.x, b.y); o.w = pack2(b.z, b.w);
            int byte = (row * BK + kk) * 2;
            byte ^= (row & 7) << 4;
            *(uint4*)((char*)xs + byte) = o;
        }
#pragma unroll
        for (int p = 0; p < 4; ++p) {
            int l  = p * 32 + (tid >> 3);
            int kk = (tid & 7) * 8;
            uint4 v = *(const uint4*)(Vh + (size_t)l * M_ + k0 + kk);
            uint4 u = *(const uint4*)(Uh + (size_t)l * M_ + k0 + kk);
            int byte = (l * BK + kk) * 2;
            byte ^= (l & 7) << 4;
            *(uint4*)((char*)vs + byte) = v;
            *(uint4*)((char*)us + byte) = u;
        }
        __syncthreads();
#pragma unroll
        for (int ksub = 0; ksub < 2; ++ksub) {
            bf16x8 afr[2];
#pragma unroll
            for (int rf = 0; rf < 2; ++rf) {
                int row = wave * 32 + rf * 16 + c;
                int byte = (row * BK + ksub * 32 + g * 8) * 2;
                byte ^= (row & 7) << 4;
                afr[rf] = *(const bf16x8*)((const char*)xs + byte);
            }
#pragma unroll
            for (int cf = 0; cf < 8; ++cf) {
                int l = cf * 16 + c;
                int byte = (l * BK + ksub * 32 + g * 8) * 2;
                byte ^= (l & 7) << 4;
                bf16x8 bv = *(const bf16x8*)((const char*)vs + byte);
                bf16x8 bu = *(const bf16x8*)((const char*)us + byte);
#pragma unroll
                for (int rf = 0; rf < 2; ++rf) {
                    accV[rf][cf] = __builtin_amdgcn_mfma_f32_16x16x32_bf16(afr[rf], bv, accV[rf][cf], 0, 0, 0);
                    accU[rf][cf] = __builtin_amdgcn_mfma_f32_16x16x32_bf16(afr[rf], bu, accU[rf][cf], 0, 0, 0);
                }
            }
        }
    }
#pragma unroll
    for (int rf = 0; rf < 2; ++rf) {
        float plog[4] = {0.f, 0.f, 0.f, 0.f};
#pragma unroll
        for (int cf = 0; cf < 8; ++cf) {
            float wvv = wl[cf * 16 + c];
#pragma unroll
            for (int i = 0; i < 4; ++i) {
                float vv = accV[rf][cf][i];
                float uu = accU[rf][cf][i];
                vv = fminf(fmaxf(vv, -20.f), 20.f);
                float e2v = __expf(2.f * vv);
                float t = __fdividef(e2v - 1.f, e2v + 1.f);
                float s = __fdividef(1.f, 1.f + __expf(-uu));
                plog[i] += t * s * wvv;
            }
        }
#pragma unroll
        for (int i = 0; i < 4; ++i) {
            float v = plog[i];
            v += __shfl_xor(v, 1);
            v += __shfl_xor(v, 2);
            v += __shfl_xor(v, 4);
            v += __shfl_xor(v, 8);
            if (c == 0) {
                int rowflat = row0 + wave * 32 + rf * 16 + g * 4 + i;
                int b = rowflat >> 12;
                int n = rowflat & (N_ - 1);
                logits[((size_t)b * H_ + h) * N_ + n] = v;
            }
        }
    }
}

// ---------------------------------------------------------------------------
// softmax^2 from TWO partial-logit halves (fast path): lg = p0 + p1.
// a = e^2/sum(e^2), e = m*exp(m*lg). Writes att in (H,B,N) order.
// ---------------------------------------------------------------------------
__global__ __launch_bounds__(256)
void softmax_att2(const float* __restrict__ pl0, const float* __restrict__ pl1,
                  const float* __restrict__ masks, float* __restrict__ att) {
    const int bh = blockIdx.x;
    const int b = bh >> 2, h = bh & 3;
    __shared__ float e2s[N_];
    __shared__ float red[4];
    const int tid = threadIdx.x;

    float sum = 0.f;
#pragma unroll
    for (int i = 0; i < N_ / 256; ++i) {
        int n = i * 256 + tid;
        size_t idx = ((size_t)b * H_ + h) * N_ + n;
        float lg = pl0[idx] + pl1[idx];
        float mv = masks[(size_t)b * N_ + n];
        float e = mv * __expf(mv * lg);
        float e2 = e * e;
        e2s[n] = e2;
        sum += e2;
    }
#pragma unroll
    for (int off = 32; off >= 1; off >>= 1) sum += __shfl_xor(sum, off);
    if ((tid & 63) == 0) red[tid >> 6] = sum;
    __syncthreads();
    float S = red[0] + red[1] + red[2] + red[3];
    float inv = 1.f / S;
#pragma unroll
    for (int i = 0; i < N_ / 256; ++i) {
        int n = i * 256 + tid;
        att[((size_t)h * B_ + b) * N_ + n] = e2s[n] * inv;
    }
}

// slow-path softmax (single logits buffer)
__global__ __launch_bounds__(256)
void softmax_att(const float* __restrict__ logits, const float* __restrict__ masks,
                 float* __restrict__ att) {
    const int bh = blockIdx.x;
    const int b = bh >> 2, h = bh & 3;
    __shared__ float e2s[N_];
    __shared__ float red[4];
    const int tid = threadIdx.x;

    float sum = 0.f;
#pragma unroll
    for (int i = 0; i < N_ / 256; ++i) {
        int n = i * 256 + tid;
        float lg = logits[((size_t)b * H_ + h) * N_ + n];
        float mv = masks[(size_t)b * N_ + n];
        float e = mv * __expf(mv * lg);
        float e2 = e * e;
        e2s[n] = e2;
        sum += e2;
    }
#pragma unroll
    for (int off = 32; off >= 1; off >>= 1) sum += __shfl_xor(sum, off);
    if ((tid & 63) == 0) red[tid >> 6] = sum;
    __syncthreads();
    float S = red[0] + red[1] + red[2] + red[3];
    float inv = 1.f / S;
#pragma unroll
    for (int i = 0; i < N_ / 256; ++i) {
        int n = i * 256 + tid;
        att[((size_t)h * B_ + b) * N_ + n] = e2s[n] * inv;
    }
}

// ---------------------------------------------------------------------------
// emb: 2-stage deterministic reduction (f32 x for full precision).
// ---------------------------------------------------------------------------
#define NCH 32
#define CHUNK (N_ / NCH)   // 128

__global__ __launch_bounds__(256)
void emb_partial(const float* __restrict__ x, const float* __restrict__ att,
                 float* __restrict__ part) {
    const int bc = blockIdx.x;
    const int b = bc >> 5, ch = bc & 31;
    __shared__ float as[H_][CHUNK];
    const int tid = threadIdx.x;

    for (int i = tid; i < H_ * CHUNK; i += 256) {
        int hh = i >> 7;
        int j  = i & (CHUNK - 1);
        as[hh][j] = att[((size_t)hh * B_ + b) * N_ + ch * CHUNK + j];
    }
    __syncthreads();

    float a0 = 0.f, a1 = 0.f, a2 = 0.f, a3 = 0.f;
    const float* xp = x + ((size_t)b * N_ + ch * CHUNK) * M_ + tid;
#pragma unroll 4
    for (int j = 0; j < CHUNK; ++j) {
        float xv = xp[(size_t)j * M_];
        a0 += as[0][j] * xv;
        a1 += as[1][j] * xv;
        a2 += as[2][j] * xv;
        a3 += as[3][j] * xv;
    }
    float* pp = part + (size_t)bc * H_ * M_ + tid;
    pp[0 * M_] = a0; pp[1 * M_] = a1; pp[2 * M_] = a2; pp[3 * M_] = a3;
}

__global__ __launch_bounds__(256)
void emb_reduce(const float* __restrict__ part, float* __restrict__ emb) {
    int idx = blockIdx.x * 256 + threadIdx.x;
    int b = idx >> 10;
    int r = idx & 1023;
    float s = 0.f;
#pragma unroll
    for (int ci = 0; ci < NCH; ++ci)
        s += part[((size_t)(b * NCH + ci)) * (H_ * M_) + r];
    emb[idx] = s;
}

// ---------------------------------------------------------------------------
extern "C" void kernel_launch(void* const* d_in, const int* in_sizes, int n_in,
                              void* d_out, int out_size, void* d_ws, size_t ws_size,
                              hipStream_t stream) {
    const float* x     = (const float*)d_in[0];
    const float* masks = (const float*)d_in[1];
    const float* V     = (const float*)d_in[2];
    const float* U     = (const float*)d_in[3];
    const float* w     = (const float*)d_in[4];

    float* att = (float*)d_out;                       // (H,B,N,1)
    float* emb = att + (size_t)H_ * B_ * N_;          // (B,H*M)

    char* ws = (char*)d_ws;
    const size_t VU_BYTES  = (size_t)128 * 4096;              // 524,288
    const size_t PL_BYTES  = (size_t)2 * B_ * H_ * N_ * 4;    // 4,194,304
    const size_t PT_BYTES  = (size_t)B_ * NCH * H_ * M_ * 4;  // 4,194,304
    const size_t NEED_FAST = VU_BYTES + PL_BYTES + PT_BYTES;

    if (ws_size >= NEED_FAST) {
        unsigned short* vuimg = (unsigned short*)ws;
        float* partL = (float*)(ws + VU_BYTES);
        float* partp = (float*)(ws + VU_BYTES + PL_BYTES);

        prep_vu_img2<<<32,   256, 0, stream>>>(V, U, vuimg);
        gemm_fast13 <<<8192, 256, 0, stream>>>(x, vuimg, w, partL);
        softmax_att2<<<B_ * H_, 256, 0, stream>>>(partL,
                                                  partL + (size_t)B_ * H_ * N_,
                                                  masks, att);
        emb_partial<<<B_ * NCH, 256, 0, stream>>>(x, att, partp);
        emb_reduce <<<(B_ * H_ * M_) / 256, 256, 0, stream>>>(partp, emb);
    } else {
        unsigned short* Vt = (unsigned short*)ws;
        unsigned short* Ut = (unsigned short*)(ws + 262144);
        float* logits = (float*)(ws + 524288);
        float* partp  = (float*)(ws + 524288 + (size_t)B_ * H_ * N_ * 4);

        prep_vu_slow<<<512, 256, 0, stream>>>(V, U, Vt, Ut);
        gemm_logits <<<4096, 256, 0, stream>>>(x, Vt, Ut, w, logits);
        softmax_att <<<B_ * H_, 256, 0, stream>>>(logits, masks, att);
        emb_partial <<<B_ * NCH, 256, 0, stream>>>(x, att, partp);
        emb_reduce  <<<(B_ * H_ * M_) / 256, 256, 0, stream>>>(partp, emb);
    }
}